// Round 16
// baseline (484.833 us; speedup 1.0000x reference)
//
#include <hip/hip_runtime.h>
#include <hip/hip_bf16.h>

// CktGNN encoder via MFMA. R16 = R11 (162us best) + duty-cycle surgery:
//  - depth-3 named B1 rotation (9 slots, 36 regs); prologue for step v+1
//    issued during gate phase of v -> loads fly across 2 barriers + phase A
//  - B2 prologue issued before GRU epilogue
//  - WnX table in LDS as f16 (epilogue = pure LDS/VALU, no global stalls)
//  - v=0 GRU streams only kt9-10 (Hin == 0)
// Model: per-block stream ~24 B/cyc is duty-limited; these fill the dead time.
// Register budget at NTH=1024 is 64 (toolchain); peak live ~58.
//   GRU ext K=352: [Hin(301) | onehot_t(26) | onehot_p(9) | 1 | pad]
//   gate ext K=320: [H(301) | onehot_p(9) | 1 | pad]

#define HS 301
#define NVT 26
#define MAXPOS 9
#define MAXN 10
#define BSZ 4096
#define VS 310
#define GS 309
#define NZ 56

#define KT1 11
#define KT2 10
#define NJT 19
#define NB1 (NJT*KT1*3*512)
#define NB2 (NJT*KT2*2*512)

typedef _Float16 f16x8 __attribute__((ext_vector_type(8)));
typedef float f32x4 __attribute__((ext_vector_type(4)));

constexpr int NTH  = 1024;   // 16 waves
constexpr int BT   = 16;
constexpr int NBLK = 256;

__device__ __forceinline__ int fragOff(int g, int k) {
  return ((k >> 5) << 10) + ((((k & 31) >> 3) << 4) + g) * 16 + ((k & 7) << 1);
}
__device__ __forceinline__ float sigm(float x) { return 1.0f / (1.0f + __expf(-x)); }
__device__ __forceinline__ float tanh_fast(float x) {
  float e = __expf(2.0f * x);
  return 1.0f - 2.0f / (e + 1.0f);
}
#define BC(x) __builtin_bit_cast(f16x8, (x))
#define BAR() { asm volatile("s_waitcnt lgkmcnt(0)" ::: "memory"); \
                __builtin_amdgcn_s_barrier(); }

// ---------------- sort ----------------
__global__ void ckt_sort(const int* __restrict__ vcount, int* __restrict__ order) {
  __shared__ int cnt[12], off[12];
  int tid = threadIdx.x;
  if (tid < 12) cnt[tid] = 0;
  __syncthreads();
  for (int g = tid; g < BSZ; g += 1024) {
    int n = vcount[g]; n = n < 1 ? 1 : (n > MAXN ? MAXN : n);
    atomicAdd(&cnt[n], 1);
  }
  __syncthreads();
  if (tid == 0) {
    int s = 0;
    for (int i = 1; i <= MAXN; ++i) { off[i] = s; s += cnt[i]; }
  }
  __syncthreads();
  for (int g = tid; g < BSZ; g += 1024) {
    int n = vcount[g]; n = n < 1 ? 1 : (n > MAXN ? MAXN : n);
    int p = atomicAdd(&off[n], 1);
    order[p] = g;
  }
}

// ---------------- prep ----------------
__global__ void ckt_prep(const float* __restrict__ Wih, const float* __restrict__ Whh,
                         const float* __restrict__ b_ih, const float* __restrict__ b_hh,
                         const float* __restrict__ Wg,  const float* __restrict__ bg,
                         const float* __restrict__ Wm,
                         const float* __restrict__ Wmu, const float* __restrict__ Wlv,
                         unsigned short* __restrict__ B1, unsigned short* __restrict__ B2,
                         float* __restrict__ WnX, float* __restrict__ bn,
                         float* __restrict__ WmuT, float* __restrict__ WlvT)
{
  int i0 = blockIdx.x * blockDim.x + threadIdx.x;
  int str = gridDim.x * blockDim.x;
  for (int i = i0; i < NB1; i += str) {
    int ii = i & 7, lane = (i >> 3) & 63;
    int r = i >> 9;
    int g3 = r % 3; r /= 3;
    int kt = r % KT1; int jt = r / KT1;
    int j = jt * 16 + (lane & 15);
    int k = kt * 32 + ((lane >> 4) << 3) + ii;
    float val = 0.f;
    if (j < HS) {
      int row = g3 * HS + j;
      if (k < HS) val = Whh[row * HS + k];
      else if (k == 336) val = (g3 < 2) ? (b_ih[row] + b_hh[row]) : b_hh[row];
      else if (g3 < 2) {
        if (k < 327)      val = Wih[row * 35 + (k - 301)];
        else if (k < 336) val = Wih[row * 35 + 26 + (k - 327)];
      }
    }
    B1[i] = __builtin_bit_cast(unsigned short, (_Float16)val);
  }
  for (int i = i0; i < NB2; i += str) {
    int ii = i & 7, lane = (i >> 3) & 63;
    int r = i >> 9;
    int gm = r % 2; r /= 2;
    int kt = r % KT2; int jt = r / KT2;
    int j = jt * 16 + (lane & 15);
    int k = kt * 32 + ((lane >> 4) << 3) + ii;
    float val = 0.f;
    if (j < HS) {
      const float* W = gm ? Wm : Wg;
      if (k < HS)       val = W[j * VS + k];
      else if (k < 310) val = W[j * VS + HS + (k - 301)];
      else if (k == 310) val = gm ? 0.f : bg[j];
    }
    B2[i] = __builtin_bit_cast(unsigned short, (_Float16)val);
  }
  for (int i = i0; i < 35 * 320; i += str) {
    int x = i / 320, j = i % 320;
    WnX[i] = (j < HS) ? Wih[(2 * HS + j) * 35 + x] : 0.f;
  }
  for (int i = i0; i < 320; i += str) bn[i] = (i < HS) ? b_ih[2 * HS + i] : 0.f;
  for (int i = i0; i < GS * NZ; i += str) {
    int k = i / NZ, o = i % NZ;
    WmuT[i] = Wmu[o * GS + k];
    WlvT[i] = Wlv[o * GS + k];
  }
}

// ---------------- main ----------------
__global__ __launch_bounds__(NTH) void ckt_main(
    const int* __restrict__ node_type, const int* __restrict__ pos,
    const int* __restrict__ adj, const int* __restrict__ vcount,
    const float* __restrict__ rin, const float* __restrict__ cin,
    const float* __restrict__ gmin,
    const float* __restrict__ W1, const float* __restrict__ b1,
    const float* __restrict__ W2, const float* __restrict__ b2,
    const float* __restrict__ bmu, const float* __restrict__ blv,
    const uint4* __restrict__ B1, const uint4* __restrict__ B2,
    const float* __restrict__ WnX, const float* __restrict__ bnG,
    const float* __restrict__ WmuT, const float* __restrict__ WlvT,
    const int* __restrict__ order,
    float* __restrict__ out)
{
  __shared__ __align__(16) _Float16 sGhist[9 * 16 * 304]; // 87.5 KB
  __shared__ __align__(16) char sAf1[KT1 * 1024];         // 11 KB
  __shared__ __align__(16) char sAf2[KT2 * 1024];         // 10 KB
  __shared__ __align__(16) _Float16 sHg[16 * 304];        // 9.5 KB
  __shared__ _Float16 sWnX[35 * 320];                     // 22.4 KB
  __shared__ float sBn[320];
  __shared__ int s_gi[16];
  __shared__ int s_t[160], s_p[160], s_n[16];
  __shared__ unsigned s_am[160];
  __shared__ int s_nmax;
  __shared__ float s_df[16][28];
  __shared__ float s_hd[16][16];
  __shared__ float s_hd2[16][8];

  const int tid  = threadIdx.x;
  const int b0   = blockIdx.x * BT;
  const int w    = tid >> 6;          // 0..15
  const int lane = tid & 63;

  if (tid < 16) s_gi[tid] = order[b0 + tid];
  __syncthreads();
  if (tid < 16) {
    int n = vcount[s_gi[tid]];
    s_n[tid] = n < 1 ? 1 : (n > MAXN ? MAXN : n);
    sHg[tid * 304 + 301] = (_Float16)0.f;
    sHg[tid * 304 + 302] = (_Float16)0.f;
    sHg[tid * 304 + 303] = (_Float16)0.f;
  }
  if (tid < 160) {
    int g = tid / 10, vv = tid % 10;
    s_t[tid] = node_type[s_gi[g] * MAXN + vv];
    s_p[tid] = pos[s_gi[g] * MAXN + vv];
  }
  if (tid < 320) sBn[tid] = bnG[tid];
  for (int i = tid; i < 35 * 320; i += NTH) sWnX[i] = (_Float16)WnX[i];
  __syncthreads();
  if (tid < 160) {
    int g = tid / 10, vv = tid % 10;
    unsigned m = 0;
    if (vv < s_n[g]) {
      for (int u = 0; u < vv; ++u)
        if (adj[s_gi[g] * 100 + u * 10 + vv]) m |= (1u << u);
    }
    s_am[tid] = m;
  }
  if (tid == 0) {
    int mx = 1;
    for (int g = 0; g < 16; ++g) mx = max(mx, s_n[g]);
    s_nmax = mx;
  }
  __syncthreads();
  const int nmax = s_nmax;

  const int lq4 = (lane >> 4) << 2;
  const int jc  = lane & 15;
  const int jt1 = w;
  const int jt2 = w + 16;             // valid if w < 3

  // cross-barrier B slots (function scope, named)
  f16x8 pA0, pA1, pA2, pB0, pB1, pB2, pC0, pC1, pC2;   // B1: 36 regs
  f16x8 qA0, qA1, qB0, qB1, qC0, qC1;                  // B2: 24 regs

#define LB1(S0, S1, S2, JT, KT) { \
    const uint4* Bp_ = B1 + (size_t)(JT) * (KT1 * 3 * 64) + lane; \
    S0 = BC(Bp_[((KT) * 3 + 0) * 64]); \
    S1 = BC(Bp_[((KT) * 3 + 1) * 64]); \
    S2 = BC(Bp_[((KT) * 3 + 2) * 64]); }
#define MF1(S0, S1, S2, KT) { \
    f16x8 av = *(const f16x8*)(sAf1 + ((KT) << 10) + (lane << 4)); \
    a0 = __builtin_amdgcn_mfma_f32_16x16x32_f16(av, S0, a0, 0, 0, 0); \
    a1 = __builtin_amdgcn_mfma_f32_16x16x32_f16(av, S1, a1, 0, 0, 0); \
    a2 = __builtin_amdgcn_mfma_f32_16x16x32_f16(av, S2, a2, 0, 0, 0); }
#define GRU_STREAM(JT) \
    MF1(pA0, pA1, pA2, 0) LB1(pA0, pA1, pA2, JT, 3) \
    MF1(pB0, pB1, pB2, 1) LB1(pB0, pB1, pB2, JT, 4) \
    MF1(pC0, pC1, pC2, 2) LB1(pC0, pC1, pC2, JT, 5) \
    MF1(pA0, pA1, pA2, 3) LB1(pA0, pA1, pA2, JT, 6) \
    MF1(pB0, pB1, pB2, 4) LB1(pB0, pB1, pB2, JT, 7) \
    MF1(pC0, pC1, pC2, 5) LB1(pC0, pC1, pC2, JT, 8) \
    MF1(pA0, pA1, pA2, 6) LB1(pA0, pA1, pA2, JT, 9) \
    MF1(pB0, pB1, pB2, 7) LB1(pB0, pB1, pB2, JT, 10) \
    MF1(pC0, pC1, pC2, 8) \
    MF1(pA0, pA1, pA2, 9) \
    MF1(pB0, pB1, pB2, 10)
#define GRU_EPI(JT) { \
    int j = (JT) * 16 + jc; \
    bool jv = j < HS; \
    _Pragma("unroll") \
    for (int q = 0; q < 4; ++q) { \
      int g = lq4 + q; \
      float inn = 0.f; \
      if (jv) { \
        int t = s_t[g * 10 + v], p = s_p[g * 10 + v]; \
        inn = sBn[j] + (float)sWnX[t * 320 + j] + (float)sWnX[(26 + p) * 320 + j]; \
      } \
      float rg = sigm(a0[q]); \
      float zg = sigm(a1[q]); \
      float ng = tanh_fast(inn + rg * a2[q]); \
      float hinv = jv ? (float)*(const _Float16*)(sAf1 + fragOff(g, j)) : 0.f; \
      float hv = (1.f - zg) * ng + zg * hinv; \
      float hval = (v < s_n[g]) ? hv : 0.f; \
      if (jv) { \
        *(_Float16*)(sAf2 + fragOff(g, j)) = (_Float16)hval; \
        if (v == s_n[g] - 1) sHg[g * 304 + j] = (_Float16)hv; \
      } \
    } }

#define LB2(S0, S1, JT, KT) { \
    const uint4* Bq_ = B2 + (size_t)(JT) * (KT2 * 2 * 64) + lane; \
    S0 = BC(Bq_[((KT) * 2 + 0) * 64]); \
    S1 = BC(Bq_[((KT) * 2 + 1) * 64]); }
#define MF2(S0, S1, KT) { \
    f16x8 av = *(const f16x8*)(sAf2 + ((KT) << 10) + (lane << 4)); \
    c0 = __builtin_amdgcn_mfma_f32_16x16x32_f16(av, S0, c0, 0, 0, 0); \
    c1 = __builtin_amdgcn_mfma_f32_16x16x32_f16(av, S1, c1, 0, 0, 0); }
#define GATE_STREAM(JT) \
    MF2(qA0, qA1, 0) LB2(qA0, qA1, JT, 3) \
    MF2(qB0, qB1, 1) LB2(qB0, qB1, JT, 4) \
    MF2(qC0, qC1, 2) LB2(qC0, qC1, JT, 5) \
    MF2(qA0, qA1, 3) LB2(qA0, qA1, JT, 6) \
    MF2(qB0, qB1, 4) LB2(qB0, qB1, JT, 7) \
    MF2(qC0, qC1, 5) LB2(qC0, qC1, JT, 8) \
    MF2(qA0, qA1, 6) LB2(qA0, qA1, JT, 9) \
    MF2(qB0, qB1, 7) \
    MF2(qC0, qC1, 8) \
    MF2(qA0, qA1, 9)
#define GATE_EPI(JT) { \
    int j = (JT) * 16 + jc; \
    if (j < HS) { \
      _Pragma("unroll") \
      for (int q = 0; q < 4; ++q) { \
        int g = lq4 + q; \
        float gg = sigm(c0[q]); \
        sGhist[(v * 16 + g) * 304 + j] = (_Float16)(gg * c1[q]); \
      } \
    } }
#define QISS(JT)  LB2(qA0, qA1, JT, 0) LB2(qB0, qB1, JT, 1) LB2(qC0, qC1, JT, 2)
#define PISS(JT)  LB1(pA0, pA1, pA2, JT, 0) LB1(pB0, pB1, pB2, JT, 1) LB1(pC0, pC1, pC2, JT, 2)
#define PISS0(JT) LB1(pA0, pA1, pA2, JT, 9) LB1(pB0, pB1, pB2, JT, 10)

  // initial prologue for v=0 (short: Hin==0, only kt9-10 carry data)
  PISS0(jt1)

  for (int v = 0; v < nmax; ++v) {
    // ---------- phase A: A-frag build (Hin sums + one-hots) ----------
    if (tid < KT1 * 64) {
      int c = tid;
      int kt = c >> 6, ln = c & 63, g = ln & 15;
      int k0 = (kt << 5) + ((ln >> 4) << 3);
      unsigned am = s_am[g * 10 + v];
      f16x8 pk;
      if (k0 + 8 <= HS) {
        float a0 = 0.f, a1 = 0.f, a2 = 0.f, a3 = 0.f;
        float a4 = 0.f, a5 = 0.f, a6 = 0.f, a7 = 0.f;
        for (int u = 0; u < v; ++u) {
          float mf = (float)((am >> u) & 1u);
          f16x8 hh = *(const f16x8*)(sGhist + (u * 16 + g) * 304 + k0);
          a0 += mf * (float)hh[0]; a1 += mf * (float)hh[1];
          a2 += mf * (float)hh[2]; a3 += mf * (float)hh[3];
          a4 += mf * (float)hh[4]; a5 += mf * (float)hh[5];
          a6 += mf * (float)hh[6]; a7 += mf * (float)hh[7];
        }
        pk[0] = (_Float16)a0; pk[1] = (_Float16)a1;
        pk[2] = (_Float16)a2; pk[3] = (_Float16)a3;
        pk[4] = (_Float16)a4; pk[5] = (_Float16)a5;
        pk[6] = (_Float16)a6; pk[7] = (_Float16)a7;
      } else {
        int t = s_t[g * 10 + v], p = s_p[g * 10 + v];
        #pragma unroll
        for (int e = 0; e < 8; ++e) {
          int k = k0 + e;
          float x = 0.f;
          if (k < HS) {
            for (int u = 0; u < v; ++u) {
              float mf = (float)((am >> u) & 1u);
              x += mf * (float)sGhist[(u * 16 + g) * 304 + k];
            }
          } else if (k < 327) x = (k - 301 == t) ? 1.f : 0.f;
          else if (k < 336)   x = (k - 327 == p) ? 1.f : 0.f;
          else if (k == 336)  x = 1.f;
          pk[e] = (_Float16)x;
        }
      }
      *(f16x8*)(sAf1 + c * 16) = pk;
    } else if (tid - KT1 * 64 < 16 * 19) {
      int i = tid - KT1 * 64;
      int g = i / 19, kk = 301 + i % 19;
      float val = (kk < 310) ? ((kk - 301 == s_p[g * 10 + v]) ? 1.f : 0.f)
                             : ((kk == 310) ? 1.f : 0.f);
      *(_Float16*)(sAf2 + fragOff(g, kk)) = (_Float16)val;
    }
    BAR();

    // ---------- GRU phase ----------
    {
      f32x4 a0 = {0.f, 0.f, 0.f, 0.f}, a1 = a0, a2 = a0;
      if (v == 0) { MF1(pA0, pA1, pA2, 9) MF1(pB0, pB1, pB2, 10) }
      else        { GRU_STREAM(jt1) }
      if (w < 3) {        // prologue for tile2 (hidden under tile1 epilogue)
        if (v == 0) { PISS0(jt2) } else { PISS(jt2) }
      } else if (v < nmax - 1) { QISS(jt1) }   // B2 prologue
      GRU_EPI(jt1)
    }
    if (w < 3) {
      f32x4 a0 = {0.f, 0.f, 0.f, 0.f}, a1 = a0, a2 = a0;
      if (v == 0) { MF1(pA0, pA1, pA2, 9) MF1(pB0, pB1, pB2, 10) }
      else        { GRU_STREAM(jt2) }
      if (v < nmax - 1) { QISS(jt1) }
      GRU_EPI(jt2)
    }
    BAR();

    // ---------- gate phase (skipped on last step) ----------
    if (v < nmax - 1) {
      {
        f32x4 c0 = {0.f, 0.f, 0.f, 0.f}, c1 = c0;
        GATE_STREAM(jt1)
        if (w < 3) { QISS(jt2) }        // tile2 B2 prologue
        else       { PISS(jt1) }        // next-step B1 prologue
        GATE_EPI(jt1)
      }
      if (w < 3) {
        f32x4 c0 = {0.f, 0.f, 0.f, 0.f}, c1 = c0;
        GATE_STREAM(jt2)
        PISS(jt1)                       // next-step B1 prologue
        GATE_EPI(jt2)
      }
    }
    BAR();
  }

  // ---------- df feature ----------
  if (tid < 16) {
    int g = tid;
    #pragma unroll
    for (int i2 = 0; i2 < 27; ++i2) s_df[g][i2] = 0.f;
    int n = s_n[g];
    int gi = s_gi[g];
    for (int vv = 0; vv < n; ++vv) {
      int p = s_p[g * 10 + vv];
      int base = gi * MAXN + vv;
      s_df[g][3 * p]     = rin[base];
      s_df[g][3 * p + 1] = cin[base];
      s_df[g][3 * p + 2] = gmin[base];
    }
  }
  __syncthreads();

  // ---------- df_enc ----------
  if (tid < 256) {
    int bb = tid >> 4, o = tid & 15;
    float a = b1[o];
    #pragma unroll
    for (int k = 0; k < 27; ++k) a = fmaf(W1[o * 27 + k], s_df[bb][k], a);
    s_hd[bb][o] = fmaxf(a, 0.f);
  }
  __syncthreads();
  if (tid < 128) {
    int bb = tid >> 3, o = tid & 7;
    float a = b2[o];
    #pragma unroll
    for (int k = 0; k < 16; ++k) a = fmaf(W2[o * 16 + k], s_hd[bb][k], a);
    s_hd2[bb][o] = a;
  }
  __syncthreads();

  // ---------- heads ----------
  if (tid < 2 * NZ) {
    bool ismu = tid < NZ;
    int oo = ismu ? tid : tid - NZ;
    const float* WT = ismu ? WmuT : WlvT;
    float acc[16];
    #pragma unroll
    for (int g = 0; g < 16; ++g) acc[g] = 0.f;
    for (int k0 = 0; k0 < 304; k0 += 8) {
      float wv[8];
      #pragma unroll
      for (int e = 0; e < 8; ++e) {
        int k = k0 + e;
        wv[e] = (k < HS) ? WT[k * NZ + oo] : 0.f;
      }
      #pragma unroll
      for (int g = 0; g < 16; ++g) {
        f16x8 hh = *(const f16x8*)(sHg + g * 304 + k0);
        #pragma unroll
        for (int e = 0; e < 8; ++e) acc[g] += wv[e] * (float)hh[e];
      }
    }
    #pragma unroll
    for (int g = 0; g < 16; ++g) {
      float a = acc[g];
      #pragma unroll
      for (int kk = 0; kk < 8; ++kk) a += WT[(HS + kk) * NZ + oo] * s_hd2[g][kk];
      a += ismu ? bmu[oo] : blv[oo];
      out[(ismu ? 0 : BSZ * NZ) + s_gi[g] * NZ + oo] = a;
    }
  }
}

extern "C" void kernel_launch(void* const* d_in, const int* in_sizes, int n_in,
                              void* d_out, int out_size, void* d_ws, size_t ws_size,
                              hipStream_t stream) {
  const int*   node_type = (const int*)d_in[0];
  const int*   pos       = (const int*)d_in[1];
  const int*   adj       = (const int*)d_in[2];
  const int*   vcount    = (const int*)d_in[3];
  const float* rin       = (const float*)d_in[4];
  const float* cin       = (const float*)d_in[5];
  const float* gmin      = (const float*)d_in[6];
  const float* Wih       = (const float*)d_in[7];
  const float* Whh       = (const float*)d_in[8];
  const float* b_ih      = (const float*)d_in[9];
  const float* b_hh      = (const float*)d_in[10];
  const float* Wg        = (const float*)d_in[11];
  const float* bg        = (const float*)d_in[12];
  const float* Wm        = (const float*)d_in[13];
  const float* W1        = (const float*)d_in[14];
  const float* b1        = (const float*)d_in[15];
  const float* W2        = (const float*)d_in[16];
  const float* b2        = (const float*)d_in[17];
  const float* Wmu       = (const float*)d_in[18];
  const float* bmu       = (const float*)d_in[19];
  const float* Wlv       = (const float*)d_in[20];
  const float* blv       = (const float*)d_in[21];

  char* wsb = (char*)d_ws;
  unsigned short* B1 = (unsigned short*)wsb;              // 642,048 B
  unsigned short* B2 = (unsigned short*)(wsb + 642048);   // 389,120 B
  float* WnX  = (float*)(wsb + 1031168);                  // 44,800 B
  float* bn   = (float*)(wsb + 1075968);                  // 1,280 B
  float* WmuT = (float*)(wsb + 1077248);                  // 69,216 B
  float* WlvT = (float*)(wsb + 1146464);                  // 69,216 B
  int*   order = (int*)(wsb + 1215680);                   // 16,384 B

  ckt_prep<<<512, 256, 0, stream>>>(Wih, Whh, b_ih, b_hh, Wg, bg, Wm, Wmu, Wlv,
                                    B1, B2, WnX, bn, WmuT, WlvT);
  ckt_sort<<<1, 1024, 0, stream>>>(vcount, order);

  ckt_main<<<NBLK, NTH, 0, stream>>>(node_type, pos, adj, vcount, rin, cin, gmin,
      W1, b1, W2, b2, bmu, blv,
      (const uint4*)B1, (const uint4*)B2, WnX, bn, WmuT, WlvT, order, (float*)d_out);
}

// Round 17
// 381.875 us; speedup vs baseline: 1.2696x; 1.2696x over previous
//
#include <hip/hip_runtime.h>
#include <hip/hip_bf16.h>

// CktGNN encoder via MFMA. R17 = R11 (162us, proven best) + zero-register-cost
// trims. HARD RULE from R12/R14/R15/R16: NTH>=512 pins 64 VGPR; any >~50 live
// regs across a barrier -> wholesale spill (WRITE explodes). So: no cross-
// barrier prefetch, no DMA; keep R11's local depth-4 named rotation.
// Trims: (1) WnX as f16 LDS table (epilogue loses 8 scattered global loads);
// (2) v=0 streams only kt9-10 (Hin==0); (3) gate double-tiles on waves 13-15
// (GRU doubles on 0-2) to spread phase tails across SIMDs; (4) constant
// one-hot k=310 prefilled once.
//   GRU ext K=352: [Hin(301) | onehot_t(26) | onehot_p(9) | 1 | pad]
//   gate ext K=320: [H(301) | onehot_p(9) | 1 | pad]

#define HS 301
#define NVT 26
#define MAXPOS 9
#define MAXN 10
#define BSZ 4096
#define VS 310
#define GS 309
#define NZ 56

#define KT1 11
#define KT2 10
#define NJT 19
#define NB1 (NJT*KT1*3*512)
#define NB2 (NJT*KT2*2*512)

typedef _Float16 f16x8 __attribute__((ext_vector_type(8)));
typedef float f32x4 __attribute__((ext_vector_type(4)));

constexpr int NTH  = 1024;   // 16 waves
constexpr int BT   = 16;
constexpr int NBLK = 256;

__device__ __forceinline__ int fragOff(int g, int k) {
  return ((k >> 5) << 10) + ((((k & 31) >> 3) << 4) + g) * 16 + ((k & 7) << 1);
}
__device__ __forceinline__ float sigm(float x) { return 1.0f / (1.0f + __expf(-x)); }
__device__ __forceinline__ float tanh_fast(float x) {
  float e = __expf(2.0f * x);
  return 1.0f - 2.0f / (e + 1.0f);
}
#define BC(x) __builtin_bit_cast(f16x8, (x))
#define BAR() { asm volatile("s_waitcnt lgkmcnt(0)" ::: "memory"); \
                __builtin_amdgcn_s_barrier(); }

// ---------------- sort ----------------
__global__ void ckt_sort(const int* __restrict__ vcount, int* __restrict__ order) {
  __shared__ int cnt[12], off[12];
  int tid = threadIdx.x;
  if (tid < 12) cnt[tid] = 0;
  __syncthreads();
  for (int g = tid; g < BSZ; g += 1024) {
    int n = vcount[g]; n = n < 1 ? 1 : (n > MAXN ? MAXN : n);
    atomicAdd(&cnt[n], 1);
  }
  __syncthreads();
  if (tid == 0) {
    int s = 0;
    for (int i = 1; i <= MAXN; ++i) { off[i] = s; s += cnt[i]; }
  }
  __syncthreads();
  for (int g = tid; g < BSZ; g += 1024) {
    int n = vcount[g]; n = n < 1 ? 1 : (n > MAXN ? MAXN : n);
    int p = atomicAdd(&off[n], 1);
    order[p] = g;
  }
}

// ---------------- prep ----------------
__global__ void ckt_prep(const float* __restrict__ Wih, const float* __restrict__ Whh,
                         const float* __restrict__ b_ih, const float* __restrict__ b_hh,
                         const float* __restrict__ Wg,  const float* __restrict__ bg,
                         const float* __restrict__ Wm,
                         const float* __restrict__ Wmu, const float* __restrict__ Wlv,
                         unsigned short* __restrict__ B1, unsigned short* __restrict__ B2,
                         float* __restrict__ WnX, float* __restrict__ bn,
                         float* __restrict__ WmuT, float* __restrict__ WlvT)
{
  int i0 = blockIdx.x * blockDim.x + threadIdx.x;
  int str = gridDim.x * blockDim.x;
  for (int i = i0; i < NB1; i += str) {
    int ii = i & 7, lane = (i >> 3) & 63;
    int r = i >> 9;
    int g3 = r % 3; r /= 3;
    int kt = r % KT1; int jt = r / KT1;
    int j = jt * 16 + (lane & 15);
    int k = kt * 32 + ((lane >> 4) << 3) + ii;
    float val = 0.f;
    if (j < HS) {
      int row = g3 * HS + j;
      if (k < HS) val = Whh[row * HS + k];
      else if (k == 336) val = (g3 < 2) ? (b_ih[row] + b_hh[row]) : b_hh[row];
      else if (g3 < 2) {
        if (k < 327)      val = Wih[row * 35 + (k - 301)];
        else if (k < 336) val = Wih[row * 35 + 26 + (k - 327)];
      }
    }
    B1[i] = __builtin_bit_cast(unsigned short, (_Float16)val);
  }
  for (int i = i0; i < NB2; i += str) {
    int ii = i & 7, lane = (i >> 3) & 63;
    int r = i >> 9;
    int gm = r % 2; r /= 2;
    int kt = r % KT2; int jt = r / KT2;
    int j = jt * 16 + (lane & 15);
    int k = kt * 32 + ((lane >> 4) << 3) + ii;
    float val = 0.f;
    if (j < HS) {
      const float* W = gm ? Wm : Wg;
      if (k < HS)       val = W[j * VS + k];
      else if (k < 310) val = W[j * VS + HS + (k - 301)];
      else if (k == 310) val = gm ? 0.f : bg[j];
    }
    B2[i] = __builtin_bit_cast(unsigned short, (_Float16)val);
  }
  for (int i = i0; i < 35 * 320; i += str) {
    int x = i / 320, j = i % 320;
    WnX[i] = (j < HS) ? Wih[(2 * HS + j) * 35 + x] : 0.f;
  }
  for (int i = i0; i < 320; i += str) bn[i] = (i < HS) ? b_ih[2 * HS + i] : 0.f;
  for (int i = i0; i < GS * NZ; i += str) {
    int k = i / NZ, o = i % NZ;
    WmuT[i] = Wmu[o * GS + k];
    WlvT[i] = Wlv[o * GS + k];
  }
}

// ---------------- main ----------------
__global__ __launch_bounds__(NTH) void ckt_main(
    const int* __restrict__ node_type, const int* __restrict__ pos,
    const int* __restrict__ adj, const int* __restrict__ vcount,
    const float* __restrict__ rin, const float* __restrict__ cin,
    const float* __restrict__ gmin,
    const float* __restrict__ W1, const float* __restrict__ b1,
    const float* __restrict__ W2, const float* __restrict__ b2,
    const float* __restrict__ bmu, const float* __restrict__ blv,
    const uint4* __restrict__ B1, const uint4* __restrict__ B2,
    const float* __restrict__ WnX, const float* __restrict__ bnG,
    const float* __restrict__ WmuT, const float* __restrict__ WlvT,
    const int* __restrict__ order,
    float* __restrict__ out)
{
  __shared__ __align__(16) _Float16 sGhist[9 * 16 * 304]; // 87.5 KB
  __shared__ __align__(16) char sAf1[KT1 * 1024];         // 11 KB
  __shared__ __align__(16) char sAf2[KT2 * 1024];         // 10 KB
  __shared__ __align__(16) _Float16 sHg[16 * 304];        // 9.5 KB
  __shared__ _Float16 sWnX[35 * 320];                     // 22.4 KB
  __shared__ float sBn[320];
  __shared__ int s_gi[16];
  __shared__ int s_t[160], s_p[160], s_n[16];
  __shared__ unsigned s_am[160];
  __shared__ int s_nmax;
  __shared__ float s_df[16][28];
  __shared__ float s_hd[16][16];
  __shared__ float s_hd2[16][8];

  const int tid  = threadIdx.x;
  const int b0   = blockIdx.x * BT;
  const int w    = tid >> 6;          // 0..15
  const int lane = tid & 63;

  if (tid < 16) s_gi[tid] = order[b0 + tid];
  __syncthreads();
  if (tid < 16) {
    int n = vcount[s_gi[tid]];
    s_n[tid] = n < 1 ? 1 : (n > MAXN ? MAXN : n);
    sHg[tid * 304 + 301] = (_Float16)0.f;
    sHg[tid * 304 + 302] = (_Float16)0.f;
    sHg[tid * 304 + 303] = (_Float16)0.f;
  }
  if (tid < 160) {
    int g = tid / 10, vv = tid % 10;
    s_t[tid] = node_type[s_gi[g] * MAXN + vv];
    s_p[tid] = pos[s_gi[g] * MAXN + vv];
  }
  if (tid < 320) sBn[tid] = bnG[tid];
  for (int i = tid; i < 35 * 320; i += NTH) sWnX[i] = (_Float16)WnX[i];
  __syncthreads();
  if (tid < 160) {
    int g = tid / 10, vv = tid % 10;
    unsigned m = 0;
    if (vv < s_n[g]) {
      for (int u = 0; u < vv; ++u)
        if (adj[s_gi[g] * 100 + u * 10 + vv]) m |= (1u << u);
    }
    s_am[tid] = m;
  }
  if (tid == 0) {
    int mx = 1;
    for (int g = 0; g < 16; ++g) mx = max(mx, s_n[g]);
    s_nmax = mx;
  }
  // constant gate one-hot element k=310 (the folded "1") — written once
  if (tid < 16) *(_Float16*)(sAf2 + fragOff(tid, 310)) = (_Float16)1.f;
  __syncthreads();
  const int nmax = s_nmax;

  const int lq4 = (lane >> 4) << 2;
  const int jc  = lane & 15;

  for (int v = 0; v < nmax; ++v) {
    // ---------- phase A: GRU A-frags + gate pos-one-hots ----------
    if (tid < KT1 * 64) {
      int c = tid;
      int kt = c >> 6, ln = c & 63, g = ln & 15;
      int k0 = (kt << 5) + ((ln >> 4) << 3);
      unsigned am = s_am[g * 10 + v];
      f16x8 pk;
      if (k0 + 8 <= HS) {
        float a0 = 0.f, a1 = 0.f, a2 = 0.f, a3 = 0.f;
        float a4 = 0.f, a5 = 0.f, a6 = 0.f, a7 = 0.f;
        for (int u = 0; u < v; ++u) {
          float mf = (float)((am >> u) & 1u);
          f16x8 hh = *(const f16x8*)(sGhist + (u * 16 + g) * 304 + k0);
          a0 += mf * (float)hh[0]; a1 += mf * (float)hh[1];
          a2 += mf * (float)hh[2]; a3 += mf * (float)hh[3];
          a4 += mf * (float)hh[4]; a5 += mf * (float)hh[5];
          a6 += mf * (float)hh[6]; a7 += mf * (float)hh[7];
        }
        pk[0] = (_Float16)a0; pk[1] = (_Float16)a1;
        pk[2] = (_Float16)a2; pk[3] = (_Float16)a3;
        pk[4] = (_Float16)a4; pk[5] = (_Float16)a5;
        pk[6] = (_Float16)a6; pk[7] = (_Float16)a7;
      } else {
        int t = s_t[g * 10 + v], p = s_p[g * 10 + v];
        #pragma unroll
        for (int e = 0; e < 8; ++e) {
          int k = k0 + e;
          float x = 0.f;
          if (k < HS) {
            for (int u = 0; u < v; ++u) {
              float mf = (float)((am >> u) & 1u);
              x += mf * (float)sGhist[(u * 16 + g) * 304 + k];
            }
          } else if (k < 327) x = (k - 301 == t) ? 1.f : 0.f;
          else if (k < 336)   x = (k - 327 == p) ? 1.f : 0.f;
          else if (k == 336)  x = 1.f;
          pk[e] = (_Float16)x;
        }
      }
      *(f16x8*)(sAf1 + c * 16) = pk;
    } else if (tid - KT1 * 64 < 16 * 9) {   // gate pos one-hots k=301..309
      int i = tid - KT1 * 64;
      int g = i / 9, kk = 301 + i % 9;
      float val = (kk - 301 == s_p[g * 10 + v]) ? 1.f : 0.f;
      *(_Float16*)(sAf2 + fragOff(g, kk)) = (_Float16)val;
    }
    BAR();

    // ---------- GRU GEMM: depth-4 named pipeline (R11) ----------
#define LB1(P0, P1, P2, KT) \
    P0 = BC(Bp[((KT) * 3 + 0) * 64]); \
    P1 = BC(Bp[((KT) * 3 + 1) * 64]); \
    P2 = BC(Bp[((KT) * 3 + 2) * 64]);
#define ST1(P0, P1, P2, KT, KTN) { \
    f16x8 av = *(const f16x8*)(sAf1 + ((KT) << 10) + (lane << 4)); \
    f16x8 c0 = P0, c1 = P1, c2 = P2; \
    LB1(P0, P1, P2, KTN) \
    a0 = __builtin_amdgcn_mfma_f32_16x16x32_f16(av, c0, a0, 0, 0, 0); \
    a1 = __builtin_amdgcn_mfma_f32_16x16x32_f16(av, c1, a1, 0, 0, 0); \
    a2 = __builtin_amdgcn_mfma_f32_16x16x32_f16(av, c2, a2, 0, 0, 0); }
#define ST1E(P0, P1, P2, KT) { \
    f16x8 av = *(const f16x8*)(sAf1 + ((KT) << 10) + (lane << 4)); \
    a0 = __builtin_amdgcn_mfma_f32_16x16x32_f16(av, P0, a0, 0, 0, 0); \
    a1 = __builtin_amdgcn_mfma_f32_16x16x32_f16(av, P1, a1, 0, 0, 0); \
    a2 = __builtin_amdgcn_mfma_f32_16x16x32_f16(av, P2, a2, 0, 0, 0); }
#define GRU_EPI(JT) { \
    int j = (JT) * 16 + jc; \
    bool jv = j < HS; \
    _Pragma("unroll") \
    for (int q = 0; q < 4; ++q) { \
      int g = lq4 + q; \
      float inn = 0.f; \
      if (jv) { \
        int t = s_t[g * 10 + v], p = s_p[g * 10 + v]; \
        inn = sBn[j] + (float)sWnX[t * 320 + j] + (float)sWnX[(26 + p) * 320 + j]; \
      } \
      float rg = sigm(a0[q]); \
      float zg = sigm(a1[q]); \
      float ng = tanh_fast(inn + rg * a2[q]); \
      float hinv = jv ? (float)*(const _Float16*)(sAf1 + fragOff(g, j)) : 0.f; \
      float hv = (1.f - zg) * ng + zg * hinv; \
      float hval = (v < s_n[g]) ? hv : 0.f; \
      if (jv) { \
        *(_Float16*)(sAf2 + fragOff(g, j)) = (_Float16)hval; \
        if (v == s_n[g] - 1) sHg[g * 304 + j] = (_Float16)hv; \
      } \
    } }
#define GRU_TILE(JT) { \
    const uint4* Bp = B1 + (size_t)(JT) * (KT1 * 3 * 64) + lane; \
    f16x8 p00, p01, p02, p10, p11, p12, p20, p21, p22, p30, p31, p32; \
    LB1(p00, p01, p02, 0) LB1(p10, p11, p12, 1) \
    LB1(p20, p21, p22, 2) LB1(p30, p31, p32, 3) \
    f32x4 a0 = {0.f, 0.f, 0.f, 0.f}, a1 = a0, a2 = a0; \
    ST1(p00, p01, p02, 0, 4) ST1(p10, p11, p12, 1, 5) \
    ST1(p20, p21, p22, 2, 6) ST1(p30, p31, p32, 3, 7) \
    ST1(p00, p01, p02, 4, 8) ST1(p10, p11, p12, 5, 9) \
    ST1(p20, p21, p22, 6, 10) \
    ST1E(p30, p31, p32, 7) ST1E(p00, p01, p02, 8) \
    ST1E(p10, p11, p12, 9) ST1E(p20, p21, p22, 10) \
    GRU_EPI(JT) }
#define GRU_TILE_V0(JT) { \
    const uint4* Bp = B1 + (size_t)(JT) * (KT1 * 3 * 64) + lane; \
    f16x8 p00, p01, p02, p10, p11, p12; \
    LB1(p00, p01, p02, 9) LB1(p10, p11, p12, 10) \
    f32x4 a0 = {0.f, 0.f, 0.f, 0.f}, a1 = a0, a2 = a0; \
    ST1E(p00, p01, p02, 9) ST1E(p10, p11, p12, 10) \
    GRU_EPI(JT) }
    if (v == 0) {
      GRU_TILE_V0(w)
      if (w < 3) GRU_TILE_V0(w + 16)
    } else {
      GRU_TILE(w)
      if (w < 3) GRU_TILE(w + 16)
    }
#undef ST1
#undef ST1E
#undef LB1
    BAR();

    // ---------- gate/mapper GEMM (doubles on waves 13-15) ----------
    if (v < nmax - 1) {
#define LB2(P0, P1, KT) \
      P0 = BC(Bp[((KT) * 2 + 0) * 64]); \
      P1 = BC(Bp[((KT) * 2 + 1) * 64]);
#define ST2(P0, P1, KT, KTN) { \
      f16x8 av = *(const f16x8*)(sAf2 + ((KT) << 10) + (lane << 4)); \
      f16x8 d0 = P0, d1 = P1; \
      LB2(P0, P1, KTN) \
      c0 = __builtin_amdgcn_mfma_f32_16x16x32_f16(av, d0, c0, 0, 0, 0); \
      c1 = __builtin_amdgcn_mfma_f32_16x16x32_f16(av, d1, c1, 0, 0, 0); }
#define ST2E(P0, P1, KT) { \
      f16x8 av = *(const f16x8*)(sAf2 + ((KT) << 10) + (lane << 4)); \
      c0 = __builtin_amdgcn_mfma_f32_16x16x32_f16(av, P0, c0, 0, 0, 0); \
      c1 = __builtin_amdgcn_mfma_f32_16x16x32_f16(av, P1, c1, 0, 0, 0); }
#define GATE_TILE(JT) { \
      const uint4* Bp = B2 + (size_t)(JT) * (KT2 * 2 * 64) + lane; \
      f16x8 q00, q01, q10, q11, q20, q21, q30, q31; \
      LB2(q00, q01, 0) LB2(q10, q11, 1) LB2(q20, q21, 2) LB2(q30, q31, 3) \
      f32x4 c0 = {0.f, 0.f, 0.f, 0.f}, c1 = c0; \
      ST2(q00, q01, 0, 4) ST2(q10, q11, 1, 5) ST2(q20, q21, 2, 6) \
      ST2(q30, q31, 3, 7) ST2(q00, q01, 4, 8) ST2(q10, q11, 5, 9) \
      ST2E(q20, q21, 6) ST2E(q30, q31, 7) ST2E(q00, q01, 8) ST2E(q10, q11, 9) \
      int j = (JT) * 16 + jc; \
      if (j < HS) { \
        _Pragma("unroll") \
        for (int q = 0; q < 4; ++q) { \
          int g = lq4 + q; \
          float gg = sigm(c0[q]); \
          sGhist[(v * 16 + g) * 304 + j] = (_Float16)(gg * c1[q]); \
        } \
      } }
      GATE_TILE(w)
      if (w >= 13) GATE_TILE(w + 3)    // tiles 16,17,18 on waves 13-15
#undef ST2
#undef ST2E
#undef LB2
#undef GATE_TILE
    }
    BAR();
  }

  // ---------- df feature ----------
  if (tid < 16) {
    int g = tid;
    #pragma unroll
    for (int i2 = 0; i2 < 27; ++i2) s_df[g][i2] = 0.f;
    int n = s_n[g];
    int gi = s_gi[g];
    for (int vv = 0; vv < n; ++vv) {
      int p = s_p[g * 10 + vv];
      int base = gi * MAXN + vv;
      s_df[g][3 * p]     = rin[base];
      s_df[g][3 * p + 1] = cin[base];
      s_df[g][3 * p + 2] = gmin[base];
    }
  }
  __syncthreads();

  // ---------- df_enc ----------
  if (tid < 256) {
    int bb = tid >> 4, o = tid & 15;
    float a = b1[o];
    #pragma unroll
    for (int k = 0; k < 27; ++k) a = fmaf(W1[o * 27 + k], s_df[bb][k], a);
    s_hd[bb][o] = fmaxf(a, 0.f);
  }
  __syncthreads();
  if (tid < 128) {
    int bb = tid >> 3, o = tid & 7;
    float a = b2[o];
    #pragma unroll
    for (int k = 0; k < 16; ++k) a = fmaf(W2[o * 16 + k], s_hd[bb][k], a);
    s_hd2[bb][o] = a;
  }
  __syncthreads();

  // ---------- heads ----------
  if (tid < 2 * NZ) {
    bool ismu = tid < NZ;
    int oo = ismu ? tid : tid - NZ;
    const float* WT = ismu ? WmuT : WlvT;
    float acc[16];
    #pragma unroll
    for (int g = 0; g < 16; ++g) acc[g] = 0.f;
    for (int k0 = 0; k0 < 304; k0 += 8) {
      float wv[8];
      #pragma unroll
      for (int e = 0; e < 8; ++e) {
        int k = k0 + e;
        wv[e] = (k < HS) ? WT[k * NZ + oo] : 0.f;
      }
      #pragma unroll
      for (int g = 0; g < 16; ++g) {
        f16x8 hh = *(const f16x8*)(sHg + g * 304 + k0);
        #pragma unroll
        for (int e = 0; e < 8; ++e) acc[g] += wv[e] * (float)hh[e];
      }
    }
    #pragma unroll
    for (int g = 0; g < 16; ++g) {
      float a = acc[g];
      #pragma unroll
      for (int kk = 0; kk < 8; ++kk) a += WT[(HS + kk) * NZ + oo] * s_hd2[g][kk];
      a += ismu ? bmu[oo] : blv[oo];
      out[(ismu ? 0 : BSZ * NZ) + s_gi[g] * NZ + oo] = a;
    }
  }
}

extern "C" void kernel_launch(void* const* d_in, const int* in_sizes, int n_in,
                              void* d_out, int out_size, void* d_ws, size_t ws_size,
                              hipStream_t stream) {
  const int*   node_type = (const int*)d_in[0];
  const int*   pos       = (const int*)d_in[1];
  const int*   adj       = (const int*)d_in[2];
  const int*   vcount    = (const int*)d_in[3];
  const float* rin       = (const float*)d_in[4];
  const float* cin       = (const float*)d_in[5];
  const float* gmin      = (const float*)d_in[6];
  const float* Wih       = (const float*)d_in[7];
  const float* Whh       = (const float*)d_in[8];
  const float* b_ih      = (const float*)d_in[9];
  const float* b_hh      = (const float*)d_in[10];
  const float* Wg        = (const float*)d_in[11];
  const float* bg        = (const float*)d_in[12];
  const float* Wm        = (const float*)d_in[13];
  const float* W1        = (const float*)d_in[14];
  const float* b1        = (const float*)d_in[15];
  const float* W2        = (const float*)d_in[16];
  const float* b2        = (const float*)d_in[17];
  const float* Wmu       = (const float*)d_in[18];
  const float* bmu       = (const float*)d_in[19];
  const float* Wlv       = (const float*)d_in[20];
  const float* blv       = (const float*)d_in[21];

  char* wsb = (char*)d_ws;
  unsigned short* B1 = (unsigned short*)wsb;              // 642,048 B
  unsigned short* B2 = (unsigned short*)(wsb + 642048);   // 389,120 B
  float* WnX  = (float*)(wsb + 1031168);                  // 44,800 B
  float* bn   = (float*)(wsb + 1075968);                  // 1,280 B
  float* WmuT = (float*)(wsb + 1077248);                  // 69,216 B
  float* WlvT = (float*)(wsb + 1146464);                  // 69,216 B
  int*   order = (int*)(wsb + 1215680);                   // 16,384 B

  ckt_prep<<<512, 256, 0, stream>>>(Wih, Whh, b_ih, b_hh, Wg, bg, Wm, Wmu, Wlv,
                                    B1, B2, WnX, bn, WmuT, WlvT);
  ckt_sort<<<1, 1024, 0, stream>>>(vcount, order);

  ckt_main<<<NBLK, NTH, 0, stream>>>(node_type, pos, adj, vcount, rin, cin, gmin,
      W1, b1, W2, b2, bmu, blv,
      (const uint4*)B1, (const uint4*)B2, WnX, bn, WmuT, WlvT, order, (float*)d_out);
}

// Round 18
// 162.051 us; speedup vs baseline: 2.9919x; 2.3565x over previous
//
#include <hip/hip_runtime.h>
#include <hip/hip_bf16.h>

// CktGNN encoder via MFMA. R18 = exact restore of R11 (proven best, 162us).
// Post-R17 conclusion: R11 sits exactly at the NTH>=512 64-VGPR cliff; every
// modification tried (R12 cross-barrier prefetch, R14 DMA, R15 fwd-Hin, R16
// prefetch-v2, R17 "free" trims) tips the allocator into wholesale B-stream
// spill (WRITE explodes 100-400MB). Loop-form tiles keep ONE register
// instance of the depth-4 pipeline; macro duplication breaks that.
// Structure: grid=256, BT=16 sorted homogeneous groups, NTH=1024 (16 waves;
// waves 0-2 double-tile), named depth-4 B register pipeline, raw-barrier-free
// (plain __syncthreads via BAR is lgkmcnt+s_barrier? no - R11 used plain
// syncthreads-equivalent barriers through the compiler).
//   GRU ext K=352: [Hin(301) | onehot_t(26) | onehot_p(9) | 1 | pad]
//   gate ext K=320: [H(301) | onehot_p(9) | 1 | pad]

#define HS 301
#define NVT 26
#define MAXPOS 9
#define MAXN 10
#define BSZ 4096
#define VS 310
#define GS 309
#define NZ 56

#define KT1 11          // GRU ext K tiles (K=352)
#define KT2 10          // gate ext K tiles (K=320)
#define NJT 19          // j tiles (ceil(301/16), covers j<304)
#define NB1 (NJT*KT1*3*512)   // f16 count
#define NB2 (NJT*KT2*2*512)   // f16 count

typedef _Float16 f16x8 __attribute__((ext_vector_type(8)));
typedef float f32x4 __attribute__((ext_vector_type(4)));

constexpr int NTH  = 1024;   // 16 waves
constexpr int BT   = 16;
constexpr int NBLK = 256;

__device__ __forceinline__ int fragOff(int g, int k) {
  // byte offset of element (row g, dim k) inside an A-fragment buffer
  return ((k >> 5) << 10) + ((((k & 31) >> 3) << 4) + g) * 16 + ((k & 7) << 1);
}
__device__ __forceinline__ float sigm(float x) { return 1.0f / (1.0f + __expf(-x)); }
__device__ __forceinline__ float tanh_fast(float x) {
  float e = __expf(2.0f * x);
  return 1.0f - 2.0f / (e + 1.0f);
}
#define BC(x) __builtin_bit_cast(f16x8, (x))

// ---------------- sort: counting sort graphs by depth n ----------------
__global__ void ckt_sort(const int* __restrict__ vcount, int* __restrict__ order) {
  __shared__ int cnt[12], off[12];
  int tid = threadIdx.x;
  if (tid < 12) cnt[tid] = 0;
  __syncthreads();
  for (int g = tid; g < BSZ; g += 1024) {
    int n = vcount[g]; n = n < 1 ? 1 : (n > MAXN ? MAXN : n);
    atomicAdd(&cnt[n], 1);
  }
  __syncthreads();
  if (tid == 0) {
    int s = 0;
    for (int i = 1; i <= MAXN; ++i) { off[i] = s; s += cnt[i]; }
  }
  __syncthreads();
  for (int g = tid; g < BSZ; g += 1024) {
    int n = vcount[g]; n = n < 1 ? 1 : (n > MAXN ? MAXN : n);
    int p = atomicAdd(&off[n], 1);
    order[p] = g;
  }
}

// ---------------- prep: pack weights into fragment order ----------------
__global__ void ckt_prep(const float* __restrict__ Wih, const float* __restrict__ Whh,
                         const float* __restrict__ b_ih, const float* __restrict__ b_hh,
                         const float* __restrict__ Wg,  const float* __restrict__ bg,
                         const float* __restrict__ Wm,
                         const float* __restrict__ Wmu, const float* __restrict__ Wlv,
                         unsigned short* __restrict__ B1, unsigned short* __restrict__ B2,
                         float* __restrict__ WnX, float* __restrict__ bn,
                         float* __restrict__ WmuT, float* __restrict__ WlvT)
{
  int i0 = blockIdx.x * blockDim.x + threadIdx.x;
  int str = gridDim.x * blockDim.x;
  // B1: [jt][kt][g3][lane][ii]
  for (int i = i0; i < NB1; i += str) {
    int ii = i & 7, lane = (i >> 3) & 63;
    int r = i >> 9;
    int g3 = r % 3; r /= 3;
    int kt = r % KT1; int jt = r / KT1;
    int j = jt * 16 + (lane & 15);
    int k = kt * 32 + ((lane >> 4) << 3) + ii;
    float val = 0.f;
    if (j < HS) {
      int row = g3 * HS + j;
      if (k < HS) val = Whh[row * HS + k];
      else if (k == 336) val = (g3 < 2) ? (b_ih[row] + b_hh[row]) : b_hh[row];
      else if (g3 < 2) {
        if (k < 327)      val = Wih[row * 35 + (k - 301)];
        else if (k < 336) val = Wih[row * 35 + 26 + (k - 327)];
      }
    }
    B1[i] = __builtin_bit_cast(unsigned short, (_Float16)val);
  }
  // B2: [jt][kt][gm][lane][ii]
  for (int i = i0; i < NB2; i += str) {
    int ii = i & 7, lane = (i >> 3) & 63;
    int r = i >> 9;
    int gm = r % 2; r /= 2;
    int kt = r % KT2; int jt = r / KT2;
    int j = jt * 16 + (lane & 15);
    int k = kt * 32 + ((lane >> 4) << 3) + ii;
    float val = 0.f;
    if (j < HS) {
      const float* W = gm ? Wm : Wg;
      if (k < HS)       val = W[j * VS + k];
      else if (k < 310) val = W[j * VS + HS + (k - 301)];
      else if (k == 310) val = gm ? 0.f : bg[j];
    }
    B2[i] = __builtin_bit_cast(unsigned short, (_Float16)val);
  }
  for (int i = i0; i < 35 * 320; i += str) {
    int x = i / 320, j = i % 320;
    WnX[i] = (j < HS) ? Wih[(2 * HS + j) * 35 + x] : 0.f;
  }
  for (int i = i0; i < 320; i += str) bn[i] = (i < HS) ? b_ih[2 * HS + i] : 0.f;
  for (int i = i0; i < GS * NZ; i += str) {
    int k = i / NZ, o = i % NZ;
    WmuT[i] = Wmu[o * GS + k];
    WlvT[i] = Wlv[o * GS + k];
  }
}

// ---------------- main ----------------
__global__ __launch_bounds__(NTH) void ckt_main(
    const int* __restrict__ node_type, const int* __restrict__ pos,
    const int* __restrict__ adj, const int* __restrict__ vcount,
    const float* __restrict__ rin, const float* __restrict__ cin,
    const float* __restrict__ gmin,
    const float* __restrict__ W1, const float* __restrict__ b1,
    const float* __restrict__ W2, const float* __restrict__ b2,
    const float* __restrict__ bmu, const float* __restrict__ blv,
    const uint4* __restrict__ B1, const uint4* __restrict__ B2,
    const float* __restrict__ WnX, const float* __restrict__ bnG,
    const float* __restrict__ WmuT, const float* __restrict__ WlvT,
    const int* __restrict__ order,
    float* __restrict__ out)
{
  __shared__ __align__(16) _Float16 sGhist[9 * 16 * 304]; // gated history, 87.5 KB
  __shared__ __align__(16) char sAf1[KT1 * 1024];         // GRU A-frags, 11 KB
  __shared__ __align__(16) char sAf2[KT2 * 1024];         // gate A-frags, 10 KB
  __shared__ __align__(16) _Float16 sHg[16 * 304];        // graph state, 9.5 KB
  __shared__ float sBn[320];
  __shared__ int s_gi[16];
  __shared__ int s_t[160], s_p[160], s_n[16];
  __shared__ unsigned s_am[160];
  __shared__ int s_nmax;
  __shared__ float s_df[16][28];
  __shared__ float s_hd[16][16];
  __shared__ float s_hd2[16][8];

  const int tid  = threadIdx.x;
  const int b0   = blockIdx.x * BT;
  const int w    = tid >> 6;          // 0..15
  const int lane = tid & 63;

  if (tid < 16) s_gi[tid] = order[b0 + tid];
  __syncthreads();
  if (tid < 16) {
    int n = vcount[s_gi[tid]];
    s_n[tid] = n < 1 ? 1 : (n > MAXN ? MAXN : n);
    sHg[tid * 304 + 301] = (_Float16)0.f;   // zero f16 pad (heads read f16x8)
    sHg[tid * 304 + 302] = (_Float16)0.f;
    sHg[tid * 304 + 303] = (_Float16)0.f;
  }
  if (tid < 160) {
    int g = tid / 10, vv = tid % 10;
    s_t[tid] = node_type[s_gi[g] * MAXN + vv];
    s_p[tid] = pos[s_gi[g] * MAXN + vv];
  }
  if (tid < 320) sBn[tid] = bnG[tid];
  __syncthreads();
  if (tid < 160) {
    int g = tid / 10, vv = tid % 10;
    unsigned m = 0;
    if (vv < s_n[g]) {
      for (int u = 0; u < vv; ++u)
        if (adj[s_gi[g] * 100 + u * 10 + vv]) m |= (1u << u);
    }
    s_am[tid] = m;
  }
  if (tid == 0) {
    int mx = 1;
    for (int g = 0; g < 16; ++g) mx = max(mx, s_n[g]);
    s_nmax = mx;
  }
  __syncthreads();
  const int nmax = s_nmax;

  const int lq4 = (lane >> 4) << 2;   // base graph row of this lane's D rows
  const int jc  = lane & 15;          // column-within-tile

  for (int v = 0; v < nmax; ++v) {
    // ---------- phase A: build GRU A-frags + gate one-hot region ----------
    if (tid < KT1 * 64) {              // 704 threads
      int c = tid;
      int kt = c >> 6, ln = c & 63, g = ln & 15;
      int k0 = (kt << 5) + ((ln >> 4) << 3);
      unsigned am = s_am[g * 10 + v];
      f16x8 pk;
      if (k0 + 8 <= HS) {               // pure Hin chunk
        float a0 = 0.f, a1 = 0.f, a2 = 0.f, a3 = 0.f;
        float a4 = 0.f, a5 = 0.f, a6 = 0.f, a7 = 0.f;
        for (int u = 0; u < v; ++u) {
          float mf = (float)((am >> u) & 1u);
          f16x8 hh = *(const f16x8*)(sGhist + (u * 16 + g) * 304 + k0);
          a0 += mf * (float)hh[0]; a1 += mf * (float)hh[1];
          a2 += mf * (float)hh[2]; a3 += mf * (float)hh[3];
          a4 += mf * (float)hh[4]; a5 += mf * (float)hh[5];
          a6 += mf * (float)hh[6]; a7 += mf * (float)hh[7];
        }
        pk[0] = (_Float16)a0; pk[1] = (_Float16)a1;
        pk[2] = (_Float16)a2; pk[3] = (_Float16)a3;
        pk[4] = (_Float16)a4; pk[5] = (_Float16)a5;
        pk[6] = (_Float16)a6; pk[7] = (_Float16)a7;
      } else {                          // boundary / one-hot region
        int t = s_t[g * 10 + v], p = s_p[g * 10 + v];
        #pragma unroll
        for (int e = 0; e < 8; ++e) {
          int k = k0 + e;
          float x = 0.f;
          if (k < HS) {
            for (int u = 0; u < v; ++u) {
              float mf = (float)((am >> u) & 1u);
              x += mf * (float)sGhist[(u * 16 + g) * 304 + k];
            }
          } else if (k < 327) x = (k - 301 == t) ? 1.f : 0.f;
          else if (k < 336)   x = (k - 327 == p) ? 1.f : 0.f;
          else if (k == 336)  x = 1.f;
          pk[e] = (_Float16)x;
        }
      }
      *(f16x8*)(sAf1 + c * 16) = pk;
    } else if (tid - KT1 * 64 < 16 * 19) {  // gate A-frag one-hots k=301..319
      int i = tid - KT1 * 64;
      int g = i / 19, kk = 301 + i % 19;
      float val = (kk < 310) ? ((kk - 301 == s_p[g * 10 + v]) ? 1.f : 0.f)
                             : ((kk == 310) ? 1.f : 0.f);
      *(_Float16*)(sAf2 + fragOff(g, kk)) = (_Float16)val;
    }
    __syncthreads();

    // ---------- GRU GEMM, jt in {w, w+16 (w<3)}: depth-4 named pipeline ----------
#define LB1(P0, P1, P2, KT) \
      P0 = BC(Bp[((KT) * 3 + 0) * 64]); \
      P1 = BC(Bp[((KT) * 3 + 1) * 64]); \
      P2 = BC(Bp[((KT) * 3 + 2) * 64]);
#define ST1(P0, P1, P2, KT, KTN) { \
      f16x8 av = *(const f16x8*)(sAf1 + (KT) * 1024 + lane * 16); \
      f16x8 c0 = P0, c1 = P1, c2 = P2; \
      LB1(P0, P1, P2, KTN) \
      a0 = __builtin_amdgcn_mfma_f32_16x16x32_f16(av, c0, a0, 0, 0, 0); \
      a1 = __builtin_amdgcn_mfma_f32_16x16x32_f16(av, c1, a1, 0, 0, 0); \
      a2 = __builtin_amdgcn_mfma_f32_16x16x32_f16(av, c2, a2, 0, 0, 0); }
#define ST1E(P0, P1, P2, KT) { \
      f16x8 av = *(const f16x8*)(sAf1 + (KT) * 1024 + lane * 16); \
      a0 = __builtin_amdgcn_mfma_f32_16x16x32_f16(av, P0, a0, 0, 0, 0); \
      a1 = __builtin_amdgcn_mfma_f32_16x16x32_f16(av, P1, a1, 0, 0, 0); \
      a2 = __builtin_amdgcn_mfma_f32_16x16x32_f16(av, P2, a2, 0, 0, 0); }
    for (int jj = w; jj < NJT; jj += 16) {
      const uint4* Bp = B1 + (size_t)jj * (KT1 * 3 * 64) + lane;
      f16x8 p00, p01, p02, p10, p11, p12, p20, p21, p22, p30, p31, p32;
      LB1(p00, p01, p02, 0) LB1(p10, p11, p12, 1)
      LB1(p20, p21, p22, 2) LB1(p30, p31, p32, 3)
      f32x4 a0 = {0.f, 0.f, 0.f, 0.f}, a1 = a0, a2 = a0;
      ST1(p00, p01, p02, 0, 4) ST1(p10, p11, p12, 1, 5)
      ST1(p20, p21, p22, 2, 6) ST1(p30, p31, p32, 3, 7)
      ST1(p00, p01, p02, 4, 8) ST1(p10, p11, p12, 5, 9)
      ST1(p20, p21, p22, 6, 10)
      ST1E(p30, p31, p32, 7) ST1E(p00, p01, p02, 8)
      ST1E(p10, p11, p12, 9) ST1E(p20, p21, p22, 10)
      // epilogue (D: row=graph=(lane>>4)*4+q, col=j=lane&15)
      int j = jj * 16 + jc;
      bool jv = j < HS;
      #pragma unroll
      for (int q = 0; q < 4; ++q) {
        int g = lq4 + q;
        float inn = 0.f;
        if (jv) {
          int t = s_t[g * 10 + v], p = s_p[g * 10 + v];
          inn = sBn[j] + WnX[t * 320 + j] + WnX[(26 + p) * 320 + j];
        }
        float rg = sigm(a0[q]);
        float zg = sigm(a1[q]);
        float ng = tanh_fast(inn + rg * a2[q]);
        float hinv = jv ? (float)*(const _Float16*)(sAf1 + fragOff(g, j)) : 0.f;
        float hv = (1.f - zg) * ng + zg * hinv;
        float hval = (v < s_n[g]) ? hv : 0.f;
        if (jv) {
          *(_Float16*)(sAf2 + fragOff(g, j)) = (_Float16)hval;
          if (v == s_n[g] - 1) sHg[g * 304 + j] = (_Float16)hv;
        }
      }
    }
#undef ST1
#undef ST1E
#undef LB1
    __syncthreads();

    // ---------- gate/mapper GEMM: depth-4 named pipeline ----------
    if (v < nmax - 1) {
#define LB2(P0, P1, KT) \
        P0 = BC(Bp[((KT) * 2 + 0) * 64]); \
        P1 = BC(Bp[((KT) * 2 + 1) * 64]);
#define ST2(P0, P1, KT, KTN) { \
        f16x8 av = *(const f16x8*)(sAf2 + (KT) * 1024 + lane * 16); \
        f16x8 d0 = P0, d1 = P1; \
        LB2(P0, P1, KTN) \
        c0 = __builtin_amdgcn_mfma_f32_16x16x32_f16(av, d0, c0, 0, 0, 0); \
        c1 = __builtin_amdgcn_mfma_f32_16x16x32_f16(av, d1, c1, 0, 0, 0); }
#define ST2E(P0, P1, KT) { \
        f16x8 av = *(const f16x8*)(sAf2 + (KT) * 1024 + lane * 16); \
        c0 = __builtin_amdgcn_mfma_f32_16x16x32_f16(av, P0, c0, 0, 0, 0); \
        c1 = __builtin_amdgcn_mfma_f32_16x16x32_f16(av, P1, c1, 0, 0, 0); }
      for (int jj = w; jj < NJT; jj += 16) {
        const uint4* Bp = B2 + (size_t)jj * (KT2 * 2 * 64) + lane;
        f16x8 q00, q01, q10, q11, q20, q21, q30, q31;
        LB2(q00, q01, 0) LB2(q10, q11, 1) LB2(q20, q21, 2) LB2(q30, q31, 3)
        f32x4 c0 = {0.f, 0.f, 0.f, 0.f}, c1 = c0;
        ST2(q00, q01, 0, 4) ST2(q10, q11, 1, 5) ST2(q20, q21, 2, 6)
        ST2(q30, q31, 3, 7) ST2(q00, q01, 4, 8) ST2(q10, q11, 5, 9)
        ST2E(q20, q21, 6) ST2E(q30, q31, 7) ST2E(q00, q01, 8) ST2E(q10, q11, 9)
        int j = jj * 16 + jc;
        if (j < HS) {
          #pragma unroll
          for (int q = 0; q < 4; ++q) {
            int g = lq4 + q;
            float gg = sigm(c0[q]);
            sGhist[(v * 16 + g) * 304 + j] = (_Float16)(gg * c1[q]);
          }
        }
      }
#undef ST2
#undef ST2E
#undef LB2
    }
    __syncthreads();
  }

  // ---------- df feature ----------
  if (tid < 16) {
    int g = tid;
    #pragma unroll
    for (int i2 = 0; i2 < 27; ++i2) s_df[g][i2] = 0.f;
    int n = s_n[g];
    int gi = s_gi[g];
    for (int vv = 0; vv < n; ++vv) {
      int p = s_p[g * 10 + vv];
      int base = gi * MAXN + vv;
      s_df[g][3 * p]     = rin[base];
      s_df[g][3 * p + 1] = cin[base];
      s_df[g][3 * p + 2] = gmin[base];
    }
  }
  __syncthreads();

  // ---------- df_enc ----------
  if (tid < 256) {
    int bb = tid >> 4, o = tid & 15;   // 16x16
    float a = b1[o];
    #pragma unroll
    for (int k = 0; k < 27; ++k) a = fmaf(W1[o * 27 + k], s_df[bb][k], a);
    s_hd[bb][o] = fmaxf(a, 0.f);
  }
  __syncthreads();
  if (tid < 128) {
    int bb = tid >> 3, o = tid & 7;
    float a = b2[o];
    #pragma unroll
    for (int k = 0; k < 16; ++k) a = fmaf(W2[o * 16 + k], s_hd[bb][k], a);
    s_hd2[bb][o] = a;
  }
  __syncthreads();

  // ---------- heads ----------
  if (tid < 2 * NZ) {
    bool ismu = tid < NZ;
    int oo = ismu ? tid : tid - NZ;
    const float* WT = ismu ? WmuT : WlvT;
    float acc[16];
    #pragma unroll
    for (int g = 0; g < 16; ++g) acc[g] = 0.f;
    for (int k0 = 0; k0 < 304; k0 += 8) {
      float wv[8];
      #pragma unroll
      for (int e = 0; e < 8; ++e) {
        int k = k0 + e;
        wv[e] = (k < HS) ? WT[k * NZ + oo] : 0.f;
      }
      #pragma unroll
      for (int g = 0; g < 16; ++g) {
        f16x8 hh = *(const f16x8*)(sHg + g * 304 + k0);
        #pragma unroll
        for (int e = 0; e < 8; ++e) acc[g] += wv[e] * (float)hh[e];
      }
    }
    #pragma unroll
    for (int g = 0; g < 16; ++g) {
      float a = acc[g];
      #pragma unroll
      for (int kk = 0; kk < 8; ++kk) a += WT[(HS + kk) * NZ + oo] * s_hd2[g][kk];
      a += ismu ? bmu[oo] : blv[oo];
      out[(ismu ? 0 : BSZ * NZ) + s_gi[g] * NZ + oo] = a;
    }
  }
}

extern "C" void kernel_launch(void* const* d_in, const int* in_sizes, int n_in,
                              void* d_out, int out_size, void* d_ws, size_t ws_size,
                              hipStream_t stream) {
  const int*   node_type = (const int*)d_in[0];
  const int*   pos       = (const int*)d_in[1];
  const int*   adj       = (const int*)d_in[2];
  const int*   vcount    = (const int*)d_in[3];
  const float* rin       = (const float*)d_in[4];
  const float* cin       = (const float*)d_in[5];
  const float* gmin      = (const float*)d_in[6];
  const float* Wih       = (const float*)d_in[7];
  const float* Whh       = (const float*)d_in[8];
  const float* b_ih      = (const float*)d_in[9];
  const float* b_hh      = (const float*)d_in[10];
  const float* Wg        = (const float*)d_in[11];
  const float* bg        = (const float*)d_in[12];
  const float* Wm        = (const float*)d_in[13];
  const float* W1        = (const float*)d_in[14];
  const float* b1        = (const float*)d_in[15];
  const float* W2        = (const float*)d_in[16];
  const float* b2        = (const float*)d_in[17];
  const float* Wmu       = (const float*)d_in[18];
  const float* bmu       = (const float*)d_in[19];
  const float* Wlv       = (const float*)d_in[20];
  const float* blv       = (const float*)d_in[21];

  // ws layout (bytes, all 16B-aligned)
  char* wsb = (char*)d_ws;
  unsigned short* B1 = (unsigned short*)wsb;              // 642,048 B
  unsigned short* B2 = (unsigned short*)(wsb + 642048);   // 389,120 B
  float* WnX  = (float*)(wsb + 1031168);                  // 44,800 B
  float* bn   = (float*)(wsb + 1075968);                  // 1,280 B
  float* WmuT = (float*)(wsb + 1077248);                  // 69,216 B
  float* WlvT = (float*)(wsb + 1146464);                  // 69,216 B
  int*   order = (int*)(wsb + 1215680);                   // 16,384 B

  ckt_prep<<<512, 256, 0, stream>>>(Wih, Whh, b_ih, b_hh, Wg, bg, Wm, Wmu, Wlv,
                                    B1, B2, WnX, bn, WmuT, WlvT);
  ckt_sort<<<1, 1024, 0, stream>>>(vcount, order);

  ckt_main<<<NBLK, NTH, 0, stream>>>(node_type, pos, adj, vcount, rin, cin, gmin,
      W1, b1, W2, b2, bmu, blv,
      (const uint4*)B1, (const uint4*)B2, WnX, bn, WmuT, WlvT, order, (float*)d_out);
}